// Round 16
// baseline (65.034 us; speedup 1.0000x reference)
//
#include <hip/hip_runtime.h>

// Head: B=4, T=4096, C=1024, H=64. out = softmax(causal((x@Wq+bq)@(x@Wk+bk)^T * C^-0.5)) @ (x@Wv+bv)
#define B_ 4
#define T_ 4096
#define C_ 1024
#define H_ 64
// C^-0.5 * log2(e): folds softmax scale into Q, moves softmax into exp2 domain.
#define QSCALE 0.045084220027780106f

typedef float  f32x4   __attribute__((ext_vector_type(4)));
typedef float  f32x2   __attribute__((ext_vector_type(2)));
typedef float  f32x16  __attribute__((ext_vector_type(16)));
typedef int    i32x4   __attribute__((ext_vector_type(4)));
typedef __bf16 bf16x8  __attribute__((ext_vector_type(8)));
typedef __bf16 bf16x4  __attribute__((ext_vector_type(4)));

#define MFMA16(a, b, c) __builtin_amdgcn_mfma_f32_16x16x32_bf16((a), (b), (c), 0, 0, 0)
#define MFMA32(a, b, c) __builtin_amdgcn_mfma_f32_32x32x16_bf16((a), (b), (c), 0, 0, 0)

// async global->LDS, 16B per lane; LDS dest is wave-uniform base + lane*16.
__device__ __forceinline__ void gl16(const void* g, void* l) {
    __builtin_amdgcn_global_load_lds(
        (const __attribute__((address_space(1))) void*)g,
        (__attribute__((address_space(3))) void*)l, 16, 0, 0);
}

__device__ __forceinline__ unsigned pk2(float a, float b) {
    __bf16 ba = (__bf16)a, bb = (__bf16)b;
    return (unsigned)__builtin_bit_cast(unsigned short, ba)
         | ((unsigned)__builtin_bit_cast(unsigned short, bb) << 16);
}

// blocks per batch for the uniform-chunk decomposition (N=6):
// sum_{g=0}^{31} ceil((2g+2)/6) = 187;  grid = 4*187 = 748
#define CPB 187
#define NCHUNK 6

// ---------------------------------------------------------------------------
// prep: Wt[mat][n][k] = W_mat[k][n] as bf16 (LDS tile transpose). 192 blocks.
// ---------------------------------------------------------------------------
__global__ __launch_bounds__(256) void prep_wt(const float* __restrict__ Wk,
                                               const float* __restrict__ Wq,
                                               const float* __restrict__ Wv,
                                               __bf16* __restrict__ Wt) {
    __shared__ float tile[16][65];
    int tid = threadIdx.x;
    int mat = blockIdx.x >> 6;
    int k0  = (blockIdx.x & 63) * 16;
    const float* W = (mat == 0) ? Wk : ((mat == 1) ? Wq : Wv);
#pragma unroll
    for (int i = 0; i < 4; ++i) {
        int e = i * 256 + tid;
        int ki = e >> 6, n = e & 63;
        tile[ki][n] = W[(size_t)(k0 + ki) * 64 + n];
    }
    __syncthreads();
#pragma unroll
    for (int i = 0; i < 4; ++i) {
        int e = i * 256 + tid;
        int n = e >> 4, kj = e & 15;
        Wt[(size_t)mat * 65536 + (size_t)n * 1024 + k0 + kj] = (__bf16)tile[kj][n];
    }
}

// ---------------------------------------------------------------------------
// proj: m97-style LDS-staged GEMM (R5 version, measured ~18.5us).
// ---------------------------------------------------------------------------
#define STAGE(xd, wd, kk) do {                                              \
    const char* xs_ = xsrc + (size_t)(kk) * 4;                              \
    gl16(xs_,          (xd) + wq * 1024);                                   \
    gl16(xs_ + 65536,  (xd) + 4096 + wq * 1024);                            \
    const char* ws_ = wsrc + (size_t)(kk) * 2;                              \
    gl16(ws_,           (wd) + wq * 1024);                                  \
    gl16(ws_ + 65536,   (wd) + 4096  + wq * 1024);                          \
    gl16(ws_ + 131072,  (wd) + 8192  + wq * 1024);                          \
    gl16(ws_ + 196608,  (wd) + 12288 + wq * 1024);                          \
    gl16(ws_ + 262144,  (wd) + 16384 + wq * 1024);                          \
    gl16(ws_ + 327680,  (wd) + 20480 + wq * 1024);                          \
} while (0)

__global__ __launch_bounds__(256) void proj_qkv(const float* __restrict__ x,
                                                const __bf16* __restrict__ Wt,
                                                const float* __restrict__ bk,
                                                const float* __restrict__ bq,
                                                const float* __restrict__ bv,
                                                __bf16* __restrict__ Kg,
                                                __bf16* __restrict__ Qg,
                                                __bf16* __restrict__ Vt) {
    __shared__ char smem[65536];

    int tid  = threadIdx.x;
    int wq   = tid >> 6;
    int lane = tid & 63;
    int lo = lane & 15, g = lane >> 4;
    int swz = lo & 7;
    int w2 = wq >> 1, wc = wq & 1;
    int r0 = w2 * 16, n0 = wc * 96;
    int row0 = blockIdx.x * 32;

    const char* xsrc = (const char*)(x + (size_t)(row0 + (tid >> 4)) * C_
                                       + (size_t)(((tid & 15) ^ ((tid >> 4) & 7)) * 4));
    const char* wsrc = (const char*)Wt + (size_t)(tid >> 3) * 2048
                                       + (size_t)(((tid & 7) ^ ((tid >> 3) & 7)) * 16);

    char* xcur = smem;          char* xnxt = smem + 8192;
    char* wcur = smem + 16384;  char* wnxt = smem + 40960;

    f32x4 acc[6];
#pragma unroll
    for (int nt = 0; nt < 6; ++nt) acc[nt] = (f32x4){0.f, 0.f, 0.f, 0.f};

    STAGE(xcur, wcur, 0);
    __syncthreads();

#pragma unroll 1
    for (int step = 0; step < 16; ++step) {
        if (step < 15) STAGE(xnxt, wnxt, (step + 1) * 64);

        bf16x8 af[2];
        const char* ap = xcur + (r0 + lo) * 256;
#pragma unroll
        for (int kc = 0; kc < 2; ++kc) {
            int ch0 = kc * 8 + g * 2;
            f32x4 a0 = *(const f32x4*)(ap + ((ch0)     ^ swz) * 16);
            f32x4 a1 = *(const f32x4*)(ap + ((ch0 + 1) ^ swz) * 16);
            bf16x8 t;
            t[0] = (__bf16)a0[0]; t[1] = (__bf16)a0[1];
            t[2] = (__bf16)a0[2]; t[3] = (__bf16)a0[3];
            t[4] = (__bf16)a1[0]; t[5] = (__bf16)a1[1];
            t[6] = (__bf16)a1[2]; t[7] = (__bf16)a1[3];
            af[kc] = t;
        }
#pragma unroll
        for (int nt = 0; nt < 6; ++nt) {
            const char* bp_ = wcur + (n0 + nt * 16 + lo) * 128;
#pragma unroll
            for (int kc = 0; kc < 2; ++kc) {
                bf16x8 bf_ = *(const bf16x8*)(bp_ + ((kc * 4 + g) ^ swz) * 16);
                acc[nt] = MFMA16(af[kc], bf_, acc[nt]);
            }
        }
        __syncthreads();
        char* t1 = xcur; xcur = xnxt; xnxt = t1;
        char* t2 = wcur; wcur = wnxt; wnxt = t2;
    }

    int b_   = row0 >> 12;
    int tloc = row0 & (T_ - 1);
#pragma unroll
    for (int nt = 0; nt < 6; ++nt) {
        int col = n0 + nt * 16 + lo;
        int mat = col >> 6, h = col & 63;
        const float* bp = (mat == 0) ? bk : ((mat == 1) ? bq : bv);
        float bb = bp[h];
        if (mat == 2) {                            // V -> transposed [B][64][T]
            bf16x4 pv;
#pragma unroll
            for (int r = 0; r < 4; ++r) pv[r] = (__bf16)(acc[nt][r] + bb);
            *(bf16x4*)(Vt + (size_t)(b_ * 64 + h) * T_ + tloc + r0 + 4 * g) = pv;
        } else if (mat == 1) {
#pragma unroll
            for (int r = 0; r < 4; ++r)
                Qg[(size_t)(row0 + r0 + 4 * g + r) * H_ + h] = (__bf16)((acc[nt][r] + bb) * QSCALE);
        } else {
#pragma unroll
            for (int r = 0; r < 4; ++r)
                Kg[(size_t)(row0 + r0 + 4 * g + r) * H_ + h] = (__bf16)(acc[nt][r] + bb);
        }
    }
}

// ---------------------------------------------------------------------------
// attn 32x32 flash iteration. Swapped QK^T: St = mfma32(A=K, B=Q) ->
// St[k][q]: col q = lane&31, row k = (reg&3)+8*(reg>>2)+4*(lane>>5) (+32*kt).
// Softmax rows lane-local (32 vals) + one shfl_xor(32). PV as
// O^T = mfma32(A=V^T, B=P^T): acc col = q = lane&31 -> alpha & 1/l
// lane-local. P^T B-frag built by pk2 + shfl_xor(32) + target-side select.
// ---------------------------------------------------------------------------
__device__ __forceinline__ void attn_iter32(const char* __restrict__ kb_,
                                            const char* __restrict__ vb_,
                                            int k0abs, int q0abs, bool domask,
                                            const bf16x8 (&qB)[4],
                                            f32x16 (&accO)[2], float& m, float& l,
                                            int lq, int h2) {
    int sw = lq & 7;
    // ---- QK^T ----
    f32x16 st[2];
#pragma unroll
    for (int kt = 0; kt < 2; ++kt) {
        int row = kt * 32 + lq;
        f32x16 z;
#pragma unroll
        for (int i = 0; i < 16; ++i) z[i] = 0.f;
        __builtin_amdgcn_s_setprio(1);
#pragma unroll
        for (int s = 0; s < 4; ++s) {
            bf16x8 ka = *(const bf16x8*)(kb_ + row * 128 + (((2 * s + h2) ^ sw) << 4));
            z = MFMA32(ka, qB[s], z);
        }
        __builtin_amdgcn_s_setprio(0);
        st[kt] = z;
    }
    if (domask) {
#pragma unroll
        for (int kt = 0; kt < 2; ++kt)
#pragma unroll
            for (int r = 0; r < 16; ++r) {
                int kabs = k0abs + kt * 32 + (r & 3) + 8 * (r >> 2) + 4 * h2;
                if (kabs > q0abs + lq) st[kt][r] = -1e30f;
            }
    }
    // ---- online softmax (exp2 domain) ----
    float mloc = -1e30f;
#pragma unroll
    for (int kt = 0; kt < 2; ++kt)
#pragma unroll
        for (int r = 0; r < 16; ++r) mloc = fmaxf(mloc, st[kt][r]);
    mloc = fmaxf(mloc, __shfl_xor(mloc, 32));
    float mnew  = fmaxf(m, mloc);
    float alpha = exp2f(m - mnew);
    float ls = 0.f;
#pragma unroll
    for (int kt = 0; kt < 2; ++kt)
#pragma unroll
        for (int r = 0; r < 16; ++r) {
            float pe = exp2f(st[kt][r] - mnew);
            st[kt][r] = pe;
            ls += pe;
        }
    ls += __shfl_xor(ls, 32);
    l = l * alpha + ls;
    m = mnew;
#pragma unroll
    for (int nt = 0; nt < 2; ++nt)
#pragma unroll
        for (int r = 0; r < 16; ++r) accO[nt][r] *= alpha;   // lane-local

    // ---- pack P to bf16 pairs: pk[kt*8 + sig*2 + gam] holds rows
    // kt*32 + 8*sig + 4*h2 + {2gam, 2gam+1}, col q = lq ----
    int pk[16];
#pragma unroll
    for (int kt = 0; kt < 2; ++kt)
#pragma unroll
        for (int sg = 0; sg < 4; ++sg)
#pragma unroll
            for (int gm = 0; gm < 2; ++gm)
                pk[kt * 8 + sg * 2 + gm] =
                    (int)pk2(st[kt][4 * sg + 2 * gm], st[kt][4 * sg + 2 * gm + 1]);

    // ---- build P^T B-fragments: slice s needs rows 16s + 8*h2 + j ----
    bf16x8 pfrag[4];
#pragma unroll
    for (int s = 0; s < 4; ++s) {
        // J = 2s (lower-target) and 2s+1 (upper-target); word idx compile-time
        int iA0 = ((2 * s) >> 2) * 8 + ((2 * s) & 3) * 2;
        int iB0 = ((2 * s + 1) >> 2) * 8 + ((2 * s + 1) & 3) * 2;
        int x0 = pk[iA0],     x1 = pk[iA0 + 1];    // J=2s, own half
        int z0 = pk[iB0],     z1 = pk[iB0 + 1];    // J=2s+1, own half
        int y0 = __shfl_xor(x0, 32), y1 = __shfl_xor(x1, 32);
        int u0 = __shfl_xor(z0, 32), u1 = __shfl_xor(z1, 32);
        // value of pk[J=2s+h2] from source half hs:
        //  lower lanes (h2=0): J=2s  -> hs0: x (own),  hs1: y (partner)
        //  upper lanes (h2=1): J=2s+1-> hs0: u (partner), hs1: z (own)
        int w0 = h2 ? u0 : x0;                     // j=0,1 (hs=0)
        int w1 = h2 ? u1 : x1;                     // j=2,3 (hs=0)
        int w2 = h2 ? z0 : y0;                     // j=4,5 (hs=1)
        int w3 = h2 ? z1 : y1;                     // j=6,7 (hs=1)
        i32x4 wv = (i32x4){w0, w1, w2, w3};
        pfrag[s] = __builtin_bit_cast(bf16x8, wv);
    }

    // ---- PV: O^T += V^T @ P^T ----
#pragma unroll
    for (int nt = 0; nt < 2; ++nt) {
        int row = nt * 32 + lq;
        __builtin_amdgcn_s_setprio(1);
#pragma unroll
        for (int s = 0; s < 4; ++s) {
            bf16x8 va = *(const bf16x8*)(vb_ + row * 128 + (((2 * s + h2) ^ sw) << 4));
            accO[nt] = MFMA32(va, pfrag[s], accO[nt]);
        }
        __builtin_amdgcn_s_setprio(0);
    }
}

// ---------------------------------------------------------------------------
// attn: 748 blocks x 4 waves (256 thr). Same decomposition as R10/R15
// (batch, 128-row q-group, kb-chunk<=6) but wave = 32 q-rows via 32x32 MFMA.
// K/V staged via global_load_lds (pre-swizzled source), 2x16KB dbuf (32KB
// total), 2-barrier counted-vmcnt phase (R15-proven). No P LDS buffer.
// Unnormalized bf16 partials + (m,l) -> ws; mergeN combines.
// ---------------------------------------------------------------------------
#define STAGE_KV(kb, buf) do {                                              \
    const char* ks_ = kgb + (size_t)(kb) * 8192;                            \
    const char* vs_ = vgb + (size_t)(kb) * 128;                             \
    gl16(ks_ + koff0, smem + (buf) + wb);                                   \
    gl16(ks_ + koff1, smem + (buf) + 4096 + wb);                            \
    gl16(vs_ + voff0, smem + 16384 + (buf) + wb);                           \
    gl16(vs_ + voff1, smem + 16384 + (buf) + 4096 + wb);                    \
} while (0)

__global__ __launch_bounds__(256, 4) void attn_fwd(const __bf16* __restrict__ Qg,
                                                   const __bf16* __restrict__ Kg,
                                                   const __bf16* __restrict__ Vt,
                                                   __bf16* __restrict__ partO,
                                                   float* __restrict__ partML) {
    // [0,16384) K dbuf (2 x 8KB), [16384,32768) V dbuf (2 x 8KB)
    __shared__ alignas(16) char smem[32768];

    int tid  = threadIdx.x;
    int w    = tid >> 6;                           // wave 0..3
    int lane = tid & 63;
    int lq = lane & 31, h2 = lane >> 5;

    int bid = blockIdx.x;
    int b   = bid / CPB;
    int u   = bid - b * CPB;
    int g = 0, cum = 0;
#pragma unroll 1
    for (; g < 32; ++g) {
        int s = (2 * g + 7) / 6;
        if (u < cum + s) break;
        cum += s;
    }
    int c    = u - cum;
    int j0   = NCHUNK * c;
    int cnt  = min(NCHUNK, 2 * g + 2 - j0);
    int mydiag = 2 * g + (w >> 1);                 // wave's diagonal kb
    int q0   = g * 128 + w * 32;                   // within-batch q base

    const char* kgb = (const char*)Kg + (size_t)b * 524288;
    const char* vgb = (const char*)Vt + (size_t)b * 524288;

    // staging: 256 threads x 16B x 2 ops = one 8KB tile; pre-swizzled source
    int r8  = tid >> 3;                            // 0..31
    int sc2 = (tid & 7) ^ (r8 & 7);
    size_t koff0 = (size_t)r8 * 128 + sc2 * 16;          // K rows 0..31
    size_t koff1 = (size_t)(r8 + 32) * 128 + sc2 * 16;   // K rows 32..63
    size_t voff0 = (size_t)r8 * 8192 + sc2 * 16;         // V rows 0..31
    size_t voff1 = (size_t)(r8 + 32) * 8192 + sc2 * 16;  // V rows 32..63
    int wb = w * 1024;

    // Q as B-fragments (already *QSCALE): q = q0+lq, d = 16s + 8*h2 + j
    const __bf16* qp = Qg + (size_t)(b * T_ + q0 + lq) * H_ + 8 * h2;
    bf16x8 qB[4];
#pragma unroll
    for (int s = 0; s < 4; ++s) qB[s] = *(const bf16x8*)(qp + 16 * s);

    f32x16 accO[2];
#pragma unroll
    for (int nt = 0; nt < 2; ++nt)
#pragma unroll
        for (int i = 0; i < 16; ++i) accO[nt][i] = 0.f;
    float m = -1e30f, l = 0.f;

    // prologue: stage kb=j0 into buf0 (4 VMEM ops per wave)
    STAGE_KV(j0, 0);

#pragma unroll 1
    for (int t = 0; t < cnt; ++t) {
        __builtin_amdgcn_s_barrier();              // compute(t-1) reads done
        if (t + 1 < cnt) {
            STAGE_KV(j0 + t + 1, ((t + 1) & 1) * 8192);
            asm volatile("s_waitcnt vmcnt(4)" ::: "memory");
        } else {
            asm volatile("s_waitcnt vmcnt(0)" ::: "memory");
        }
        __builtin_amdgcn_s_barrier();              // all waves' stage(t) landed
        __builtin_amdgcn_sched_barrier(0);
        int kb = j0 + t;
        if (kb <= mydiag)                          // wave-uniform causal skip
            attn_iter32(smem + (t & 1) * 8192, smem + 16384 + (t & 1) * 8192,
                        kb * 64, q0, kb == mydiag, qB, accO, m, l, lq, h2);
    }

    // epilogue: accO[nt][reg] = O^T[h][q=lq], h = nt*32 + (reg&3)+8*(reg>>2)+4*h2
    __bf16* po = partO + (size_t)bid * 8192;       // [128][64]
    int q = w * 32 + lq;
#pragma unroll
    for (int nt = 0; nt < 2; ++nt)
#pragma unroll
        for (int sg = 0; sg < 4; ++sg) {
            bf16x4 pv;
#pragma unroll
            for (int cc = 0; cc < 4; ++cc) pv[cc] = (__bf16)accO[nt][4 * sg + cc];
            *(bf16x4*)(po + q * 64 + nt * 32 + 8 * sg + 4 * h2) = pv;
        }
    if (h2 == 0) {
        partML[bid * 256 + q * 2 + 0] = m;
        partML[bid * 256 + q * 2 + 1] = l;
    }
}

// ---------------------------------------------------------------------------
// mergeN: online LSE-merge of the variable-count (<=11) chunk partials.
// ---------------------------------------------------------------------------
__global__ __launch_bounds__(256) void mergeN(const __bf16* __restrict__ partO,
                                              const float* __restrict__ partML,
                                              float* __restrict__ out) {
    int e = blockIdx.x * 256 + threadIdx.x;        // 0 .. 1048575
    int row = e >> 6, h = e & 63;
    int b = row >> 12, rl = row & 4095;
    int g = rl >> 7, r128 = rl & 127;
    int cum = 0;
#pragma unroll 1
    for (int gg = 0; gg < g; ++gg) cum += (2 * gg + 7) / 6;
    int S = (2 * g + 7) / 6;
    int base = b * CPB + cum;

    float M = -1e30f, L = 0.f, O = 0.f;
#pragma unroll 1
    for (int c2 = 0; c2 < S; ++c2) {
        f32x2 mlv = *(const f32x2*)(partML + (base + c2) * 256 + r128 * 2);
        float oc = (float)partO[(size_t)(base + c2) * 8192 + r128 * 64 + h];
        float Mn = fmaxf(M, mlv[0]);
        float s0 = exp2f(M - Mn), s1 = exp2f(mlv[0] - Mn);
        L = L * s0 + mlv[1] * s1;
        O = O * s0 + oc * s1;
        M = Mn;
    }
    out[e] = O / L;
}

// ---------------------------------------------------------------------------
extern "C" void kernel_launch(void* const* d_in, const int* in_sizes, int n_in,
                              void* d_out, int out_size, void* d_ws, size_t ws_size,
                              hipStream_t stream) {
    const float* x  = (const float*)d_in[0];
    const float* Wk = (const float*)d_in[1];
    const float* bk = (const float*)d_in[2];
    const float* Wq = (const float*)d_in[3];
    const float* bq = (const float*)d_in[4];
    const float* Wv = (const float*)d_in[5];
    const float* bv = (const float*)d_in[6];

    char* ws = (char*)d_ws;
    // ws: Wt 384K | Kg 2M | Qg 2M | Vt 2M | partO 748*16KB=11.97M | partML 748KB
    __bf16* Wt = (__bf16*)(ws);
    __bf16* Kg = (__bf16*)(ws + 393216);
    __bf16* Qg = (__bf16*)(ws + 393216 + 2097152);
    __bf16* Vt = (__bf16*)(ws + 393216 + 2 * 2097152);
    __bf16* partO  = (__bf16*)(ws + 6684672);
    float*  partML = (float*)(ws + 6684672 + 12255232);
    float* out = (float*)d_out;

    prep_wt<<<192, 256, 0, stream>>>(Wk, Wq, Wv, Wt);
    proj_qkv<<<512, 256, 0, stream>>>(x, Wt, bk, bq, bv, Kg, Qg, Vt);
    attn_fwd<<<4 * CPB, 256, 0, stream>>>(Qg, Kg, Vt, partO, partML);
    mergeN<<<4096, 256, 0, stream>>>(partO, partML, out);
}

// Round 17
// 58.765 us; speedup vs baseline: 1.1067x; 1.1067x over previous
//
#include <hip/hip_runtime.h>

// Head: B=4, T=4096, C=1024, H=64. out = softmax(causal((x@Wq+bq)@(x@Wk+bk)^T * C^-0.5)) @ (x@Wv+bv)
#define B_ 4
#define T_ 4096
#define C_ 1024
#define H_ 64
// C^-0.5 * log2(e): folds softmax scale into Q, moves softmax into exp2 domain.
#define QSCALE 0.045084220027780106f

typedef float  f32x4  __attribute__((ext_vector_type(4)));
typedef float  f32x2  __attribute__((ext_vector_type(2)));
typedef __bf16 bf16x8 __attribute__((ext_vector_type(8)));
typedef __bf16 bf16x4 __attribute__((ext_vector_type(4)));

#define MFMA16(a, b, c) __builtin_amdgcn_mfma_f32_16x16x32_bf16((a), (b), (c), 0, 0, 0)

// async global->LDS, 16B per lane; LDS dest is wave-uniform base + lane*16.
__device__ __forceinline__ void gl16(const void* g, void* l) {
    __builtin_amdgcn_global_load_lds(
        (const __attribute__((address_space(1))) void*)g,
        (__attribute__((address_space(3))) void*)l, 16, 0, 0);
}

// blocks per batch for the uniform-chunk decomposition (N=6):
// sum_{g=0}^{31} ceil((2g+2)/6) = 187;  grid = 4*187 = 748
#define CPB 187
#define NCHUNK 6

// ---------------------------------------------------------------------------
// prep: Wt[mat][n][k] = W_mat[k][n] as bf16 (LDS tile transpose). 192 blocks.
// ---------------------------------------------------------------------------
__global__ __launch_bounds__(256) void prep_wt(const float* __restrict__ Wk,
                                               const float* __restrict__ Wq,
                                               const float* __restrict__ Wv,
                                               __bf16* __restrict__ Wt) {
    __shared__ float tile[16][65];
    int tid = threadIdx.x;
    int mat = blockIdx.x >> 6;
    int k0  = (blockIdx.x & 63) * 16;
    const float* W = (mat == 0) ? Wk : ((mat == 1) ? Wq : Wv);
#pragma unroll
    for (int i = 0; i < 4; ++i) {
        int e = i * 256 + tid;
        int ki = e >> 6, n = e & 63;
        tile[ki][n] = W[(size_t)(k0 + ki) * 64 + n];
    }
    __syncthreads();
#pragma unroll
    for (int i = 0; i < 4; ++i) {
        int e = i * 256 + tid;
        int n = e >> 4, kj = e & 15;
        Wt[(size_t)mat * 65536 + (size_t)n * 1024 + k0 + kj] = (__bf16)tile[kj][n];
    }
}

// ---------------------------------------------------------------------------
// proj: LDS-staged GEMM, BM=64 (halves W L2 streaming vs BM=32), BN=192,
// BK=64. 256 blocks x 512 threads (8 waves) -> 2 blocks/CU, 16 waves/CU.
// global_load_lds staging, pre-swizzled source, double-buffered.
// ---------------------------------------------------------------------------
#define STAGE(xd, wd, kk) do {                                              \
    const char* xs_ = xsrc + (size_t)(kk) * 4;                              \
    gl16(xs_,           (xd) + wq * 1024);                                  \
    gl16(xs_ + 131072,  (xd) + 8192 + wq * 1024);                           \
    const char* ws_ = wsrc + (size_t)(kk) * 2;                              \
    gl16(ws_,           (wd) + wq * 1024);                                  \
    gl16(ws_ + 131072,  (wd) + 8192  + wq * 1024);                          \
    gl16(ws_ + 262144,  (wd) + 16384 + wq * 1024);                          \
} while (0)

__global__ __launch_bounds__(512) void proj_qkv(const float* __restrict__ x,
                                                const __bf16* __restrict__ Wt,
                                                const float* __restrict__ bk,
                                                const float* __restrict__ bq,
                                                const float* __restrict__ bv,
                                                __bf16* __restrict__ Kg,
                                                __bf16* __restrict__ Qg,
                                                __bf16* __restrict__ Vt) {
    // x tile: [64 r][64 f32] = 16KB, byte = r*256 + ((c)^(r&7))*16
    // W tile: [192 n][64 bf16] = 24KB, byte = n*128 + ((c)^(n&7))*16
    __shared__ char smem[81920];

    int tid  = threadIdx.x;
    int wq   = tid >> 6;
    int lane = tid & 63;
    int lo = lane & 15, g = lane >> 4;
    int swz = lo & 7;
    int w2 = wq >> 1, wc = wq & 1;
    int r0 = w2 * 16, n0 = wc * 96;
    int row0 = blockIdx.x * 64;

    const char* xsrc = (const char*)(x + (size_t)(row0 + (tid >> 4)) * C_
                                       + (size_t)(((tid & 15) ^ ((tid >> 4) & 7)) * 4));
    const char* wsrc = (const char*)Wt + (size_t)(tid >> 3) * 2048
                                       + (size_t)(((tid & 7) ^ ((tid >> 3) & 7)) * 16);

    char* xcur = smem;          char* xnxt = smem + 16384;
    char* wcur = smem + 32768;  char* wnxt = smem + 57344;

    f32x4 acc[6];
#pragma unroll
    for (int nt = 0; nt < 6; ++nt) acc[nt] = (f32x4){0.f, 0.f, 0.f, 0.f};

    STAGE(xcur, wcur, 0);
    __syncthreads();

#pragma unroll 1
    for (int step = 0; step < 16; ++step) {
        if (step < 15) STAGE(xnxt, wnxt, (step + 1) * 64);

        bf16x8 af[2];
        const char* ap = xcur + (r0 + lo) * 256;
#pragma unroll
        for (int kc = 0; kc < 2; ++kc) {
            int ch0 = kc * 8 + g * 2;
            f32x4 a0 = *(const f32x4*)(ap + ((ch0)     ^ swz) * 16);
            f32x4 a1 = *(const f32x4*)(ap + ((ch0 + 1) ^ swz) * 16);
            bf16x8 t;
            t[0] = (__bf16)a0[0]; t[1] = (__bf16)a0[1];
            t[2] = (__bf16)a0[2]; t[3] = (__bf16)a0[3];
            t[4] = (__bf16)a1[0]; t[5] = (__bf16)a1[1];
            t[6] = (__bf16)a1[2]; t[7] = (__bf16)a1[3];
            af[kc] = t;
        }
#pragma unroll
        for (int nt = 0; nt < 6; ++nt) {
            const char* bp_ = wcur + (n0 + nt * 16 + lo) * 128;
#pragma unroll
            for (int kc = 0; kc < 2; ++kc) {
                bf16x8 bf_ = *(const bf16x8*)(bp_ + ((kc * 4 + g) ^ swz) * 16);
                acc[nt] = MFMA16(af[kc], bf_, acc[nt]);
            }
        }
        __syncthreads();
        char* t1 = xcur; xcur = xnxt; xnxt = t1;
        char* t2 = wcur; wcur = wnxt; wnxt = t2;
    }

    int b_   = row0 >> 12;
    int tloc = row0 & (T_ - 1);
#pragma unroll
    for (int nt = 0; nt < 6; ++nt) {
        int col = n0 + nt * 16 + lo;
        int mat = col >> 6, h = col & 63;
        const float* bp = (mat == 0) ? bk : ((mat == 1) ? bq : bv);
        float bb = bp[h];
        if (mat == 2) {                            // V -> transposed [B][64][T]
            bf16x4 pv;
#pragma unroll
            for (int r = 0; r < 4; ++r) pv[r] = (__bf16)(acc[nt][r] + bb);
            *(bf16x4*)(Vt + (size_t)(b_ * 64 + h) * T_ + tloc + r0 + 4 * g) = pv;
        } else if (mat == 1) {
#pragma unroll
            for (int r = 0; r < 4; ++r)
                Qg[(size_t)(row0 + r0 + 4 * g + r) * H_ + h] = (__bf16)((acc[nt][r] + bb) * QSCALE);
        } else {
#pragma unroll
            for (int r = 0; r < 4; ++r)
                Kg[(size_t)(row0 + r0 + 4 * g + r) * H_ + h] = (__bf16)(acc[nt][r] + bb);
        }
    }
}

// ---------------------------------------------------------------------------
// attn flash iteration, K and V from swizzled LDS (R10-proven, unchanged).
// Swapped QK^T: St[k][q] = mfma(K, Q) so softmax rows are lane-local.
// ---------------------------------------------------------------------------
__device__ __forceinline__ void attn_iter_lds(const char* __restrict__ kb_,
                                              const char* __restrict__ vb_,
                                              int k0abs, int q0, bool domask,
                                              bf16x8 qb0, bf16x8 qb1,
                                              f32x4 (&acc)[4], float& m, float& l,
                                              char* pl, int lo, int g) {
    f32x4 st[4];
#pragma unroll
    for (int kt = 0; kt < 4; ++kt) {
        int row = kt * 16 + lo, sw = row & 7;
        bf16x8 ka0 = *(const bf16x8*)(kb_ + row * 128 + ((g ^ sw) << 4));
        bf16x8 ka1 = *(const bf16x8*)(kb_ + row * 128 + (((g + 4) ^ sw) << 4));
        f32x4 z = (f32x4){0.f, 0.f, 0.f, 0.f};
        __builtin_amdgcn_s_setprio(1);
        z = MFMA16(ka0, qb0, z);                   // St[k][q]: col=q=lo, row=k=4g+r
        z = MFMA16(ka1, qb1, z);
        __builtin_amdgcn_s_setprio(0);
        st[kt] = z;
    }
    if (domask) {
#pragma unroll
        for (int kt = 0; kt < 4; ++kt)
#pragma unroll
            for (int r = 0; r < 4; ++r) {
                int kabs = k0abs + kt * 16 + 4 * g + r;
                if (kabs > q0 + lo) st[kt][r] = -1e30f;
            }
    }
    float mloc = -1e30f;
#pragma unroll
    for (int kt = 0; kt < 4; ++kt)
#pragma unroll
        for (int r = 0; r < 4; ++r) mloc = fmaxf(mloc, st[kt][r]);
    mloc = fmaxf(mloc, __shfl_xor(mloc, 16));
    mloc = fmaxf(mloc, __shfl_xor(mloc, 32));
    float mnew  = fmaxf(m, mloc);
    float alpha = exp2f(m - mnew);
    float ls = 0.f;
#pragma unroll
    for (int kt = 0; kt < 4; ++kt)
#pragma unroll
        for (int r = 0; r < 4; ++r) {
            float pe = exp2f(st[kt][r] - mnew);
            st[kt][r] = pe;
            ls += pe;
        }
    ls += __shfl_xor(ls, 16);
    ls += __shfl_xor(ls, 32);
    l = l * alpha + ls;
    m = mnew;
#pragma unroll
    for (int r = 0; r < 4; ++r) {
        float ar = __shfl(alpha, 4 * g + r);
#pragma unroll
        for (int ht = 0; ht < 4; ++ht) acc[ht][r] *= ar;
    }
#pragma unroll
    for (int kt = 0; kt < 4; ++kt) {
        bf16x4 pk;
#pragma unroll
        for (int r = 0; r < 4; ++r) pk[r] = (__bf16)st[kt][r];
        int waddr = (lo * 128 + kt * 32 + g * 8) ^ ((lo & 7) << 4);
        *(bf16x4*)(pl + waddr) = pk;
    }
#pragma unroll
    for (int c2 = 0; c2 < 2; ++c2) {
        int raddr = (lo * 128 + c2 * 64 + g * 16) ^ ((lo & 7) << 4);
        bf16x8 pa = *(const bf16x8*)(pl + raddr);
        __builtin_amdgcn_s_setprio(1);
#pragma unroll
        for (int ht = 0; ht < 4; ++ht) {
            int row = ht * 16 + lo, sw = row & 7;
            bf16x8 vb = *(const bf16x8*)(vb_ + row * 128 + (((c2 * 4 + g) ^ sw) << 4));
            acc[ht] = MFMA16(pa, vb, acc[ht]);
        }
        __builtin_amdgcn_s_setprio(0);
    }
}

// ---------------------------------------------------------------------------
// attn: 748 blocks x 8 waves (R10 decomposition, 48KB LDS -> 3 blocks/CU)
// with a 2-barrier counted-vmcnt phase (T4 / m201 pattern), R15-proven:
//   barrier_pre -> issue stage(t+1) -> vmcnt(2) -> barrier_mid -> compute(t)
// No vmcnt(0) drain in the loop (only last iter).
// ---------------------------------------------------------------------------
__global__ __launch_bounds__(512) void attn_fwd(const __bf16* __restrict__ Qg,
                                                const __bf16* __restrict__ Kg,
                                                const __bf16* __restrict__ Vt,
                                                __bf16* __restrict__ partO,
                                                float* __restrict__ partML) {
    // [0,16384) K dbuf, [16384,32768) V dbuf, [32768,49152) P bufs (8 x 2KB)
    __shared__ alignas(16) char smem[49152];

    int tid  = threadIdx.x;
    int w    = tid >> 6;
    int lane = tid & 63;
    int lo = lane & 15, gq = lane >> 4;

    int bid = blockIdx.x;
    int b   = bid / CPB;
    int u   = bid - b * CPB;
    int g = 0, cum = 0;
#pragma unroll 1
    for (; g < 32; ++g) {
        int s = (2 * g + 7) / 6;
        if (u < cum + s) break;
        cum += s;
    }
    int c    = u - cum;
    int j0   = NCHUNK * c;
    int cnt  = min(NCHUNK, 2 * g + 2 - j0);
    int mydiag = 2 * g + (w >> 2);                 // wave's diagonal kb
    int q0   = g * 128 + w * 16;                   // within-batch q base

    const char* kgb = (const char*)Kg + (size_t)b * 524288;
    const char* vgb = (const char*)Vt + (size_t)b * 524288;

    // staging: 512 threads x 16B = one 8KB tile; pre-swizzled source
    int sr = tid >> 3;
    int sc2 = (tid & 7) ^ (sr & 7);
    int koff = sr * 128 + sc2 * 16;                // Kg row stride 128B
    int voff = sr * 8192 + sc2 * 16;               // Vt row stride 8192B
    char* pl = smem + 32768 + w * 2048;

    const __bf16* qp = Qg + (size_t)(b * T_ + q0 + lo) * H_ + gq * 8;
    bf16x8 qb0 = *(const bf16x8*)(qp);
    bf16x8 qb1 = *(const bf16x8*)(qp + 32);

    f32x4 acc[4];
#pragma unroll
    for (int ht = 0; ht < 4; ++ht) acc[ht] = (f32x4){0.f, 0.f, 0.f, 0.f};
    float m = -1e30f, l = 0.f;

    // prologue: stage kb=j0 into buf0 (2 VMEM ops per wave)
    gl16(kgb + (size_t)j0 * 8192 + koff, smem + w * 1024);
    gl16(vgb + (size_t)j0 * 128 + voff, smem + 16384 + w * 1024);

#pragma unroll 1
    for (int t = 0; t < cnt; ++t) {
        __builtin_amdgcn_s_barrier();              // compute(t-1) reads done
        if (t + 1 < cnt) {
            int kb = j0 + t + 1;
            int nb = ((t + 1) & 1) * 8192;
            gl16(kgb + (size_t)kb * 8192 + koff, smem + nb + w * 1024);
            gl16(vgb + (size_t)kb * 128 + voff, smem + 16384 + nb + w * 1024);
            asm volatile("s_waitcnt vmcnt(2)" ::: "memory");
        } else {
            asm volatile("s_waitcnt vmcnt(0)" ::: "memory");
        }
        __builtin_amdgcn_s_barrier();              // all waves' stage(t) landed
        __builtin_amdgcn_sched_barrier(0);
        int kb = j0 + t;
        if (kb <= mydiag)                          // wave-uniform causal skip
            attn_iter_lds(smem + (t & 1) * 8192, smem + 16384 + (t & 1) * 8192,
                          kb * 64, q0, kb == mydiag,
                          qb0, qb1, acc, m, l, pl, lo, gq);
    }

    // epilogue: unnormalized bf16 partials + (m,l)
    __bf16* po = partO + (size_t)bid * 8192;       // [128][64]
#pragma unroll
    for (int ht = 0; ht < 4; ++ht)
#pragma unroll
        for (int r = 0; r < 4; ++r)
            po[(w * 16 + 4 * gq + r) * 64 + ht * 16 + lo] = (__bf16)acc[ht][r];
    if (gq == 0) {
        partML[bid * 256 + (w * 16 + lo) * 2 + 0] = m;
        partML[bid * 256 + (w * 16 + lo) * 2 + 1] = l;
    }
}

// ---------------------------------------------------------------------------
// mergeN: online LSE-merge, vectorized: thread = 8 h-columns of one row,
// bf16x8 (16B) partO loads (coalesced), 2x f32x4 stores.
// ---------------------------------------------------------------------------
__global__ __launch_bounds__(256) void mergeN(const __bf16* __restrict__ partO,
                                              const float* __restrict__ partML,
                                              float* __restrict__ out) {
    int e8 = blockIdx.x * 256 + threadIdx.x;       // 0 .. 131071
    int row = e8 >> 3, hc = (e8 & 7) * 8;
    int b = row >> 12, rl = row & 4095;
    int g = rl >> 7, r128 = rl & 127;
    int cum = 0;
#pragma unroll 1
    for (int gg = 0; gg < g; ++gg) cum += (2 * gg + 7) / 6;
    int S = (2 * g + 7) / 6;
    int base = b * CPB + cum;

    float M = -1e30f, L = 0.f;
    float O[8];
#pragma unroll
    for (int i = 0; i < 8; ++i) O[i] = 0.f;
#pragma unroll 1
    for (int c2 = 0; c2 < S; ++c2) {
        f32x2 mlv = *(const f32x2*)(partML + (base + c2) * 256 + r128 * 2);
        bf16x8 ov = *(const bf16x8*)(partO + (size_t)(base + c2) * 8192 + r128 * 64 + hc);
        float Mn = fmaxf(M, mlv[0]);
        float s0 = exp2f(M - Mn), s1 = exp2f(mlv[0] - Mn);
        L = L * s0 + mlv[1] * s1;
#pragma unroll
        for (int i = 0; i < 8; ++i) O[i] = O[i] * s0 + (float)ov[i] * s1;
        M = Mn;
    }
    float inv = 1.f / L;
    f32x4 o0 = (f32x4){O[0] * inv, O[1] * inv, O[2] * inv, O[3] * inv};
    f32x4 o1 = (f32x4){O[4] * inv, O[5] * inv, O[6] * inv, O[7] * inv};
    float* dst = out + (size_t)row * 64 + hc;
    *(f32x4*)(dst) = o0;
    *(f32x4*)(dst + 4) = o1;
}

// ---------------------------------------------------------------------------
extern "C" void kernel_launch(void* const* d_in, const int* in_sizes, int n_in,
                              void* d_out, int out_size, void* d_ws, size_t ws_size,
                              hipStream_t stream) {
    const float* x  = (const float*)d_in[0];
    const float* Wk = (const float*)d_in[1];
    const float* bk = (const float*)d_in[2];
    const float* Wq = (const float*)d_in[3];
    const float* bq = (const float*)d_in[4];
    const float* Wv = (const float*)d_in[5];
    const float* bv = (const float*)d_in[6];

    char* ws = (char*)d_ws;
    // ws: Wt 384K | Kg 2M | Qg 2M | Vt 2M | partO 748*16KB=11.97M | partML 748KB
    __bf16* Wt = (__bf16*)(ws);
    __bf16* Kg = (__bf16*)(ws + 393216);
    __bf16* Qg = (__bf16*)(ws + 393216 + 2097152);
    __bf16* Vt = (__bf16*)(ws + 393216 + 2 * 2097152);
    __bf16* partO  = (__bf16*)(ws + 6684672);
    float*  partML = (float*)(ws + 6684672 + 12255232);
    float* out = (float*)d_out;

    prep_wt<<<192, 256, 0, stream>>>(Wk, Wq, Wv, Wt);
    proj_qkv<<<256, 512, 0, stream>>>(x, Wt, bk, bq, bv, Kg, Qg, Vt);
    attn_fwd<<<4 * CPB, 512, 0, stream>>>(Qg, Kg, Vt, partO, partML);
    mergeN<<<512, 256, 0, stream>>>(partO, partML, out);
}

// Round 18
// 57.193 us; speedup vs baseline: 1.1371x; 1.0275x over previous
//
#include <hip/hip_runtime.h>

// Head: B=4, T=4096, C=1024, H=64. out = softmax(causal((x@Wq+bq)@(x@Wk+bk)^T * C^-0.5)) @ (x@Wv+bv)
#define B_ 4
#define T_ 4096
#define C_ 1024
#define H_ 64
// C^-0.5 * log2(e): folds softmax scale into Q, moves softmax into exp2 domain.
#define QSCALE 0.045084220027780106f

typedef float  f32x4  __attribute__((ext_vector_type(4)));
typedef float  f32x2  __attribute__((ext_vector_type(2)));
typedef __bf16 bf16x8 __attribute__((ext_vector_type(8)));
typedef __bf16 bf16x4 __attribute__((ext_vector_type(4)));

#define MFMA16(a, b, c) __builtin_amdgcn_mfma_f32_16x16x32_bf16((a), (b), (c), 0, 0, 0)

// async global->LDS, 16B per lane; LDS dest is wave-uniform base + lane*16.
__device__ __forceinline__ void gl16(const void* g, void* l) {
    __builtin_amdgcn_global_load_lds(
        (const __attribute__((address_space(1))) void*)g,
        (__attribute__((address_space(3))) void*)l, 16, 0, 0);
}

// blocks per batch for the uniform-chunk decomposition (N=6):
// sum_{g=0}^{31} ceil((2g+2)/6) = 187;  grid = 4*187 = 748
#define CPB 187
#define NCHUNK 6

// ---------------------------------------------------------------------------
// prep: Wt[mat][n][k] = W_mat[k][n] as bf16 (LDS tile transpose). 192 blocks.
// ---------------------------------------------------------------------------
__global__ __launch_bounds__(256) void prep_wt(const float* __restrict__ Wk,
                                               const float* __restrict__ Wq,
                                               const float* __restrict__ Wv,
                                               __bf16* __restrict__ Wt) {
    __shared__ float tile[16][65];
    int tid = threadIdx.x;
    int mat = blockIdx.x >> 6;
    int k0  = (blockIdx.x & 63) * 16;
    const float* W = (mat == 0) ? Wk : ((mat == 1) ? Wq : Wv);
#pragma unroll
    for (int i = 0; i < 4; ++i) {
        int e = i * 256 + tid;
        int ki = e >> 6, n = e & 63;
        tile[ki][n] = W[(size_t)(k0 + ki) * 64 + n];
    }
    __syncthreads();
#pragma unroll
    for (int i = 0; i < 4; ++i) {
        int e = i * 256 + tid;
        int n = e >> 4, kj = e & 15;
        Wt[(size_t)mat * 65536 + (size_t)n * 1024 + k0 + kj] = (__bf16)tile[kj][n];
    }
}

// ---------------------------------------------------------------------------
// proj: LDS-staged GEMM, BM=64, BN=192, BK=64. 256 blocks x 512 threads
// (8 waves) -> 2 blocks/CU, 16 waves/CU. global_load_lds staging,
// pre-swizzled source, double-buffered.  (R17-proven, ~14us)
// ---------------------------------------------------------------------------
#define STAGE(xd, wd, kk) do {                                              \
    const char* xs_ = xsrc + (size_t)(kk) * 4;                              \
    gl16(xs_,           (xd) + wq * 1024);                                  \
    gl16(xs_ + 131072,  (xd) + 8192 + wq * 1024);                           \
    const char* ws_ = wsrc + (size_t)(kk) * 2;                              \
    gl16(ws_,           (wd) + wq * 1024);                                  \
    gl16(ws_ + 131072,  (wd) + 8192  + wq * 1024);                          \
    gl16(ws_ + 262144,  (wd) + 16384 + wq * 1024);                          \
} while (0)

__global__ __launch_bounds__(512) void proj_qkv(const float* __restrict__ x,
                                                const __bf16* __restrict__ Wt,
                                                const float* __restrict__ bk,
                                                const float* __restrict__ bq,
                                                const float* __restrict__ bv,
                                                __bf16* __restrict__ Kg,
                                                __bf16* __restrict__ Qg,
                                                __bf16* __restrict__ Vt) {
    __shared__ char smem[81920];

    int tid  = threadIdx.x;
    int wq   = tid >> 6;
    int lane = tid & 63;
    int lo = lane & 15, g = lane >> 4;
    int swz = lo & 7;
    int w2 = wq >> 1, wc = wq & 1;
    int r0 = w2 * 16, n0 = wc * 96;
    int row0 = blockIdx.x * 64;

    const char* xsrc = (const char*)(x + (size_t)(row0 + (tid >> 4)) * C_
                                       + (size_t)(((tid & 15) ^ ((tid >> 4) & 7)) * 4));
    const char* wsrc = (const char*)Wt + (size_t)(tid >> 3) * 2048
                                       + (size_t)(((tid & 7) ^ ((tid >> 3) & 7)) * 16);

    char* xcur = smem;          char* xnxt = smem + 16384;
    char* wcur = smem + 32768;  char* wnxt = smem + 57344;

    f32x4 acc[6];
#pragma unroll
    for (int nt = 0; nt < 6; ++nt) acc[nt] = (f32x4){0.f, 0.f, 0.f, 0.f};

    STAGE(xcur, wcur, 0);
    __syncthreads();

#pragma unroll 1
    for (int step = 0; step < 16; ++step) {
        if (step < 15) STAGE(xnxt, wnxt, (step + 1) * 64);

        bf16x8 af[2];
        const char* ap = xcur + (r0 + lo) * 256;
#pragma unroll
        for (int kc = 0; kc < 2; ++kc) {
            int ch0 = kc * 8 + g * 2;
            f32x4 a0 = *(const f32x4*)(ap + ((ch0)     ^ swz) * 16);
            f32x4 a1 = *(const f32x4*)(ap + ((ch0 + 1) ^ swz) * 16);
            bf16x8 t;
            t[0] = (__bf16)a0[0]; t[1] = (__bf16)a0[1];
            t[2] = (__bf16)a0[2]; t[3] = (__bf16)a0[3];
            t[4] = (__bf16)a1[0]; t[5] = (__bf16)a1[1];
            t[6] = (__bf16)a1[2]; t[7] = (__bf16)a1[3];
            af[kc] = t;
        }
#pragma unroll
        for (int nt = 0; nt < 6; ++nt) {
            const char* bp_ = wcur + (n0 + nt * 16 + lo) * 128;
#pragma unroll
            for (int kc = 0; kc < 2; ++kc) {
                bf16x8 bf_ = *(const bf16x8*)(bp_ + ((kc * 4 + g) ^ swz) * 16);
                acc[nt] = MFMA16(af[kc], bf_, acc[nt]);
            }
        }
        __syncthreads();
        char* t1 = xcur; xcur = xnxt; xnxt = t1;
        char* t2 = wcur; wcur = wnxt; wnxt = t2;
    }

    int b_   = row0 >> 12;
    int tloc = row0 & (T_ - 1);
#pragma unroll
    for (int nt = 0; nt < 6; ++nt) {
        int col = n0 + nt * 16 + lo;
        int mat = col >> 6, h = col & 63;
        const float* bp = (mat == 0) ? bk : ((mat == 1) ? bq : bv);
        float bb = bp[h];
        if (mat == 2) {                            // V -> transposed [B][64][T]
            bf16x4 pv;
#pragma unroll
            for (int r = 0; r < 4; ++r) pv[r] = (__bf16)(acc[nt][r] + bb);
            *(bf16x4*)(Vt + (size_t)(b_ * 64 + h) * T_ + tloc + r0 + 4 * g) = pv;
        } else if (mat == 1) {
#pragma unroll
            for (int r = 0; r < 4; ++r)
                Qg[(size_t)(row0 + r0 + 4 * g + r) * H_ + h] = (__bf16)((acc[nt][r] + bb) * QSCALE);
        } else {
#pragma unroll
            for (int r = 0; r < 4; ++r)
                Kg[(size_t)(row0 + r0 + 4 * g + r) * H_ + h] = (__bf16)(acc[nt][r] + bb);
        }
    }
}

// ---------------------------------------------------------------------------
// attn flash iteration, K and V from swizzled LDS (R10-proven) + defer-max
// (T13): skip the alpha rescale (4 shfl + 16 mul + max update) unless some
// row's max grew by > 11.5 (exp2 domain; P then bounded by 2^11.5, which
// bf16 partials absorb -- relative error unchanged after l-normalization).
// Swapped QK^T: St[k][q] = mfma(K, Q) so softmax rows are lane-local.
// ---------------------------------------------------------------------------
__device__ __forceinline__ void attn_iter_lds(const char* __restrict__ kb_,
                                              const char* __restrict__ vb_,
                                              int k0abs, int q0, bool domask,
                                              bf16x8 qb0, bf16x8 qb1,
                                              f32x4 (&acc)[4], float& m, float& l,
                                              char* pl, int lo, int g) {
    f32x4 st[4];
#pragma unroll
    for (int kt = 0; kt < 4; ++kt) {
        int row = kt * 16 + lo, sw = row & 7;
        bf16x8 ka0 = *(const bf16x8*)(kb_ + row * 128 + ((g ^ sw) << 4));
        bf16x8 ka1 = *(const bf16x8*)(kb_ + row * 128 + (((g + 4) ^ sw) << 4));
        f32x4 z = (f32x4){0.f, 0.f, 0.f, 0.f};
        __builtin_amdgcn_s_setprio(1);
        z = MFMA16(ka0, qb0, z);                   // St[k][q]: col=q=lo, row=k=4g+r
        z = MFMA16(ka1, qb1, z);
        __builtin_amdgcn_s_setprio(0);
        st[kt] = z;
    }
    if (domask) {
#pragma unroll
        for (int kt = 0; kt < 4; ++kt)
#pragma unroll
            for (int r = 0; r < 4; ++r) {
                int kabs = k0abs + kt * 16 + 4 * g + r;
                if (kabs > q0 + lo) st[kt][r] = -1e30f;
            }
    }
    float mloc = -1e30f;
#pragma unroll
    for (int kt = 0; kt < 4; ++kt)
#pragma unroll
        for (int r = 0; r < 4; ++r) mloc = fmaxf(mloc, st[kt][r]);
    mloc = fmaxf(mloc, __shfl_xor(mloc, 16));
    mloc = fmaxf(mloc, __shfl_xor(mloc, 32));
    if (__any(mloc > m + 11.5f)) {                 // defer-max: rarely taken
        float mnew  = fmaxf(m, mloc);
        float alpha = exp2f(m - mnew);
        l *= alpha;
        m = mnew;
#pragma unroll
        for (int r = 0; r < 4; ++r) {
            float ar = __shfl(alpha, 4 * g + r);
#pragma unroll
            for (int ht = 0; ht < 4; ++ht) acc[ht][r] *= ar;
        }
    }
    float ls = 0.f;
#pragma unroll
    for (int kt = 0; kt < 4; ++kt)
#pragma unroll
        for (int r = 0; r < 4; ++r) {
            float pe = exp2f(st[kt][r] - m);
            st[kt][r] = pe;
            ls += pe;
        }
    ls += __shfl_xor(ls, 16);
    ls += __shfl_xor(ls, 32);
    l += ls;
#pragma unroll
    for (int kt = 0; kt < 4; ++kt) {
        bf16x4 pk;
#pragma unroll
        for (int r = 0; r < 4; ++r) pk[r] = (__bf16)st[kt][r];
        int waddr = (lo * 128 + kt * 32 + g * 8) ^ ((lo & 7) << 4);
        *(bf16x4*)(pl + waddr) = pk;
    }
#pragma unroll
    for (int c2 = 0; c2 < 2; ++c2) {
        int raddr = (lo * 128 + c2 * 64 + g * 16) ^ ((lo & 7) << 4);
        bf16x8 pa = *(const bf16x8*)(pl + raddr);
        __builtin_amdgcn_s_setprio(1);
#pragma unroll
        for (int ht = 0; ht < 4; ++ht) {
            int row = ht * 16 + lo, sw = row & 7;
            bf16x8 vb = *(const bf16x8*)(vb_ + row * 128 + (((c2 * 4 + g) ^ sw) << 4));
            acc[ht] = MFMA16(pa, vb, acc[ht]);
        }
        __builtin_amdgcn_s_setprio(0);
    }
}

// ---------------------------------------------------------------------------
// attn: 748 blocks x 8 waves (R10 decomposition, 48KB LDS -> 3 blocks/CU)
// with a 2-barrier counted-vmcnt phase (T4 / m201 pattern), R15-proven:
//   barrier_pre -> issue stage(t+1) -> vmcnt(2) -> barrier_mid -> compute(t)
// ---------------------------------------------------------------------------
__global__ __launch_bounds__(512) void attn_fwd(const __bf16* __restrict__ Qg,
                                                const __bf16* __restrict__ Kg,
                                                const __bf16* __restrict__ Vt,
                                                __bf16* __restrict__ partO,
                                                float* __restrict__ partML) {
    // [0,16384) K dbuf, [16384,32768) V dbuf, [32768,49152) P bufs (8 x 2KB)
    __shared__ alignas(16) char smem[49152];

    int tid  = threadIdx.x;
    int w    = tid >> 6;
    int lane = tid & 63;
    int lo = lane & 15, gq = lane >> 4;

    int bid = blockIdx.x;
    int b   = bid / CPB;
    int u   = bid - b * CPB;
    int g = 0, cum = 0;
#pragma unroll 1
    for (; g < 32; ++g) {
        int s = (2 * g + 7) / 6;
        if (u < cum + s) break;
        cum += s;
    }
    int c    = u - cum;
    int j0   = NCHUNK * c;
    int cnt  = min(NCHUNK, 2 * g + 2 - j0);
    int mydiag = 2 * g + (w >> 2);                 // wave's diagonal kb
    int q0   = g * 128 + w * 16;                   // within-batch q base

    const char* kgb = (const char*)Kg + (size_t)b * 524288;
    const char* vgb = (const char*)Vt + (size_t)b * 524288;

    // staging: 512 threads x 16B = one 8KB tile; pre-swizzled source
    int sr = tid >> 3;
    int sc2 = (tid & 7) ^ (sr & 7);
    int koff = sr * 128 + sc2 * 16;                // Kg row stride 128B
    int voff = sr * 8192 + sc2 * 16;               // Vt row stride 8192B
    char* pl = smem + 32768 + w * 2048;

    const __bf16* qp = Qg + (size_t)(b * T_ + q0 + lo) * H_ + gq * 8;
    bf16x8 qb0 = *(const bf16x8*)(qp);
    bf16x8 qb1 = *(const bf16x8*)(qp + 32);

    f32x4 acc[4];
#pragma unroll
    for (int ht = 0; ht < 4; ++ht) acc[ht] = (f32x4){0.f, 0.f, 0.f, 0.f};
    float m = -1e30f, l = 0.f;

    // prologue: stage kb=j0 into buf0 (2 VMEM ops per wave)
    gl16(kgb + (size_t)j0 * 8192 + koff, smem + w * 1024);
    gl16(vgb + (size_t)j0 * 128 + voff, smem + 16384 + w * 1024);

#pragma unroll 1
    for (int t = 0; t < cnt; ++t) {
        __builtin_amdgcn_s_barrier();              // compute(t-1) reads done
        if (t + 1 < cnt) {
            int kb = j0 + t + 1;
            int nb = ((t + 1) & 1) * 8192;
            gl16(kgb + (size_t)kb * 8192 + koff, smem + nb + w * 1024);
            gl16(vgb + (size_t)kb * 128 + voff, smem + 16384 + nb + w * 1024);
            asm volatile("s_waitcnt vmcnt(2)" ::: "memory");
        } else {
            asm volatile("s_waitcnt vmcnt(0)" ::: "memory");
        }
        __builtin_amdgcn_s_barrier();              // all waves' stage(t) landed
        __builtin_amdgcn_sched_barrier(0);
        int kb = j0 + t;
        if (kb <= mydiag)                          // wave-uniform causal skip
            attn_iter_lds(smem + (t & 1) * 8192, smem + 16384 + (t & 1) * 8192,
                          kb * 64, q0, kb == mydiag,
                          qb0, qb1, acc, m, l, pl, lo, gq);
    }

    // epilogue: unnormalized bf16 partials + (m,l)
    __bf16* po = partO + (size_t)bid * 8192;       // [128][64]
#pragma unroll
    for (int ht = 0; ht < 4; ++ht)
#pragma unroll
        for (int r = 0; r < 4; ++r)
            po[(w * 16 + 4 * gq + r) * 64 + ht * 16 + lo] = (__bf16)acc[ht][r];
    if (gq == 0) {
        partML[bid * 256 + (w * 16 + lo) * 2 + 0] = m;
        partML[bid * 256 + (w * 16 + lo) * 2 + 1] = l;
    }
}

// ---------------------------------------------------------------------------
// mergeN: online LSE-merge, vectorized (bf16x8 loads, f32x4 stores);
// closed-form chunk prefix: cum(g) = sum_{j=1..g} ceil(j/3).
// ---------------------------------------------------------------------------
__global__ __launch_bounds__(256) void mergeN(const __bf16* __restrict__ partO,
                                              const float* __restrict__ partML,
                                              float* __restrict__ out) {
    int e8 = blockIdx.x * 256 + threadIdx.x;       // 0 .. 131071
    int row = e8 >> 3, hc = (e8 & 7) * 8;
    int b = row >> 12, rl = row & 4095;
    int g = rl >> 7, r128 = rl & 127;
    int a = g / 3, bb3 = g - 3 * a;
    int cum = 3 * (a * (a + 1) / 2) + bb3 * (a + 1);   // sum ceil(j/3), j<=g
    int S = (2 * g + 7) / 6;
    int base = b * CPB + cum;

    float M = -1e30f, L = 0.f;
    float O[8];
#pragma unroll
    for (int i = 0; i < 8; ++i) O[i] = 0.f;
#pragma unroll 1
    for (int c2 = 0; c2 < S; ++c2) {
        f32x2 mlv = *(const f32x2*)(partML + (base + c2) * 256 + r128 * 2);
        bf16x8 ov = *(const bf16x8*)(partO + (size_t)(base + c2) * 8192 + r128 * 64 + hc);
        float Mn = fmaxf(M, mlv[0]);
        float s0 = exp2f(M - Mn), s1 = exp2f(mlv[0] - Mn);
        L = L * s0 + mlv[1] * s1;
#pragma unroll
        for (int i = 0; i < 8; ++i) O[i] = O[i] * s0 + (float)ov[i] * s1;
        M = Mn;
    }
    float inv = 1.f / L;
    f32x4 o0 = (f32x4){O[0] * inv, O[1] * inv, O[2] * inv, O[3] * inv};
    f32x4 o1 = (f32x4){O[4] * inv, O[5] * inv, O[6] * inv, O[7] * inv};
    float* dst = out + (size_t)row * 64 + hc;
    *(f32x4*)(dst) = o0;
    *(f32x4*)(dst + 4) = o1;
}

// ---------------------------------------------------------------------------
extern "C" void kernel_launch(void* const* d_in, const int* in_sizes, int n_in,
                              void* d_out, int out_size, void* d_ws, size_t ws_size,
                              hipStream_t stream) {
    const float* x  = (const float*)d_in[0];
    const float* Wk = (const float*)d_in[1];
    const float* bk = (const float*)d_in[2];
    const float* Wq = (const float*)d_in[3];
    const float* bq = (const float*)d_in[4];
    const float* Wv = (const float*)d_in[5];
    const float* bv = (const float*)d_in[6];

    char* ws = (char*)d_ws;
    // ws: Wt 384K | Kg 2M | Qg 2M | Vt 2M | partO 748*16KB=11.97M | partML 748KB
    __bf16* Wt = (__bf16*)(ws);
    __bf16* Kg = (__bf16*)(ws + 393216);
    __bf16* Qg = (__bf16*)(ws + 393216 + 2097152);
    __bf16* Vt = (__bf16*)(ws + 393216 + 2 * 2097152);
    __bf16* partO  = (__bf16*)(ws + 6684672);
    float*  partML = (float*)(ws + 6684672 + 12255232);
    float* out = (float*)d_out;

    prep_wt<<<192, 256, 0, stream>>>(Wk, Wq, Wv, Wt);
    proj_qkv<<<256, 512, 0, stream>>>(x, Wt, bk, bq, bv, Kg, Qg, Vt);
    attn_fwd<<<4 * CPB, 512, 0, stream>>>(Qg, Kg, Vt, partO, partML);
    mergeN<<<512, 256, 0, stream>>>(partO, partML, out);
}